// Round 10
// baseline (254.709 us; speedup 1.0000x reference)
//
#include <hip/hip_runtime.h>
#include <hip/hip_bf16.h>

#define IN_F 512
#define OUT_F 512
#define LATD 512
#define RES 64
#define BATCH 8
#define EPSV 1e-8f

static constexpr float C_LIN  = 0.04419417382415922f;   // 1/sqrt(512)
static constexpr float C_CONV = 0.014731391274719739f;  // 1/sqrt(512*9)

typedef __attribute__((ext_vector_type(8)))  short short8;
typedef __attribute__((ext_vector_type(16))) float f32x16;

union BF { __hip_bfloat16 h; short s; };

__device__ __forceinline__ void async_load16(const char* g, char* l) {
  __builtin_amdgcn_global_load_lds(
      (const __attribute__((address_space(1))) unsigned int*)g,
      (__attribute__((address_space(3))) unsigned int*)l, 16, 0, 0);
}

// ================= K1: prep_w (all blocks) + compute_s (<128) ==========
// wb layout: [(c*4+ob)][tap][half][o128][8ch] bf16 ; w2[o][i] = sum_t w^2
__global__ void k_prep(const float* __restrict__ w_conv,
                       short* __restrict__ wb,
                       float* __restrict__ w2,
                       const float* __restrict__ latent,
                       const float* __restrict__ w_lin,
                       const float* __restrict__ b_lin,
                       float* __restrict__ s) {
  const int t = blockIdx.x * 256 + threadIdx.x;   // 262144: o*512 + i
  {
    const int o = t >> 9;
    const int i = t & 511;
    const float* src = w_conv + (size_t)t * 9;
    const int c = i >> 4, hf0 = (i >> 3) & 1, ch = i & 7;
    const int ob = o >> 7, ol = o & 127;
    short* dst = wb + (size_t)(c * 4 + ob) * 18432 + hf0 * 1024 + ol * 8 + ch;
    float sum = 0.f;
#pragma unroll
    for (int tap = 0; tap < 9; ++tap) {
      const float v = src[tap] * C_CONV;
      sum += v * v;
      BF cv; cv.h = __float2bfloat16(v);
      dst[tap * 2048] = cv.s;
    }
    w2[t] = sum;
  }

  // s = latent @ (w_lin*C).T + b_lin : blocks 0..127, wave w -> row i = blk*4 + w
  if (blockIdx.x < 128) {
    const int wv = threadIdx.x >> 6, lane = threadIdx.x & 63;
    const int i = blockIdx.x * 4 + wv;
    const float4* wl = (const float4*)(w_lin + (size_t)i * LATD);
    const float4 w0 = wl[lane * 2], w1 = wl[lane * 2 + 1];
    float acc[BATCH];
#pragma unroll
    for (int b = 0; b < BATCH; ++b) {
      const float4* lt = (const float4*)(latent + (size_t)b * LATD);
      const float4 l0 = lt[lane * 2], l1 = lt[lane * 2 + 1];
      acc[b] = w0.x * l0.x + w0.y * l0.y + w0.z * l0.z + w0.w * l0.w +
               w1.x * l1.x + w1.y * l1.y + w1.z * l1.z + w1.w * l1.w;
    }
#pragma unroll
    for (int b = 0; b < BATCH; ++b) {
      float v = acc[b];
#pragma unroll
      for (int off = 32; off > 0; off >>= 1) v += __shfl_down(v, off);
      if (lane == 0) s[b * IN_F + i] = v * C_LIN + b_lin[i];
    }
  }
}

// ===== K2: sigma_inv[b][o] = rsqrt(sum_i w2[o][i]*s[b][i]^2 + eps) =====
__global__ void k_sigma(const float* __restrict__ w2,
                        const float* __restrict__ s,
                        float* __restrict__ sigma_inv) {
  const int o = blockIdx.x * 4 + (threadIdx.x >> 6);
  const int lane = threadIdx.x & 63;
  float acc[BATCH];
#pragma unroll
  for (int b = 0; b < BATCH; ++b) acc[b] = 0.f;
#pragma unroll
  for (int k = 0; k < 8; ++k) {
    const int i = k * 64 + lane;
    const float w = w2[o * IN_F + i];
#pragma unroll
    for (int b = 0; b < BATCH; ++b) {
      const float sv = s[b * IN_F + i];
      acc[b] += w * sv * sv;
    }
  }
#pragma unroll
  for (int b = 0; b < BATCH; ++b) {
    float v = acc[b];
#pragma unroll
    for (int off = 32; off > 0; off >>= 1) v += __shfl_down(v, off);
    if (lane == 0) sigma_inv[b * OUT_F + o] = rsqrtf(v + EPSV);
  }
}

// ---- staging helpers: modulate-on-the-fly (x fp32 -> bf16*s into LDS) ----
// Wave-uniform decomposition: hf = wave&1, hr = k*4 + (wave>>1), col = lane.
__device__ __forceinline__ void stage_x_load(
    const float* __restrict__ xb, const float* __restrict__ s,
    int b, int icn, int h0, int wave, int lane, int hf_s,
    float xv[3][8], float ss[8]) {
#pragma unroll
  for (int j = 0; j < 8; ++j)
    ss[j] = s[b * IN_F + icn * 16 + hf_s * 8 + j];   // block/wave-uniform
#pragma unroll
  for (int k = 0; k < 3; ++k) {
    const int hr = k * 4 + (wave >> 1);
    const int h = h0 - 1 + hr;
    const bool ok = (k < 2 || wave < 4) && (h >= 0) && (h < 64);  // wave-uniform
#pragma unroll
    for (int j = 0; j < 8; ++j)
      xv[k][j] = ok ? xb[((size_t)(icn * 16 + hf_s * 8 + j)) * (RES * RES)
                        + h * RES + lane]
                    : 0.f;
  }
}

__device__ __forceinline__ void stage_x_write(
    char* xd, int wave, int lane, int hf_s,
    const float xv[3][8], const float ss[8]) {
#pragma unroll
  for (int k = 0; k < 3; ++k) {
    if (k < 2 || wave < 4) {       // wave-uniform guard
      const int hr = k * 4 + (wave >> 1);
      short8 pk;
#pragma unroll
      for (int j = 0; j < 8; ++j) {
        BF cv; cv.h = __float2bfloat16(xv[k][j] * ss[j]);
        pk[j] = cv.s;
      }
      *(short8*)(xd + ((hr * 132) + hf_s * 66 + (lane + 1)) * 16) = pk;
    }
  }
}

// ---------------- main implicit-GEMM conv, modulate fused ----------------
// Block: 128 o x (8 rows x 64 cols) px, 8 waves (512 thr) -> 2 waves/SIMD.
// x staged directly from fp32 input: per-thread coalesced loads issued one
// full chunk ahead (~8000 cyc cover), * s (wave-uniform scalars), cvt bf16,
// ds_write into the same [10][2][66][16B] layout. xmp intermediate deleted.
// Per-chunk per-XCD x working set = 256 KB -> L2-resident.
__global__ __launch_bounds__(512, 2)
void k_conv(const float* __restrict__ x,
            const float* __restrict__ s,
            const short* __restrict__ wbg,
            const float* __restrict__ sigma_inv,
            const float* __restrict__ b_conv,
            float* __restrict__ out) {
  __shared__ __align__(16) char lds[115968];  // x: 2*21120 @0, w: 2*36864 @42240
  const int l = blockIdx.x;
  const int ob = (l >> 3) & 3;
  const int b  = l & 7;
  const int h0 = (l >> 5) * 8;
  const int o0 = ob * 128;
  const int tid = threadIdx.x;
  const int wave = tid >> 6, lane = tid & 63;
  const int l31 = lane & 31, half = lane >> 5;
  const int oh = wave >> 2;             // o-half
  const int q  = wave & 3;              // px quadrant
  const int r0 = (q >> 1) * 4;
  const int c0 = (q & 1) * 32;
  const int st = (wave >> 2) & 1;       // dw-phase stagger
  const int dseq[3] = {st, st + 1, st ? 0 : 2};
  const int hf_s = wave & 1;            // staging half (wave-uniform)

  f32x16 acc[2][4];
#pragma unroll
  for (int i = 0; i < 2; ++i)
#pragma unroll
    for (int j = 0; j < 4; ++j)
#pragma unroll
      for (int r = 0; r < 16; ++r) acc[i][j][r] = 0.f;

  const float* xb = x + (size_t)b * IN_F * (RES * RES);
  const char* wsrc0 = (const char*)wbg + (size_t)ob * 36864;

  float xv[3][8];
  float ss[8];

  // ---- prologue: stage chunk 0 (x via registers, w via gload_lds) ----
  stage_x_load(xb, s, b, 0, h0, wave, lane, hf_s, xv, ss);
#pragma unroll
  for (int k = 0; k < 4; ++k) {
    const int j = tid + k * 512;
    async_load16(wsrc0 + j * 16, lds + 42240 + j * 16);
  }
  if (tid < 256) { const int j = 2048 + tid; async_load16(wsrc0 + j * 16, lds + 42240 + j * 16); }
  stage_x_write(lds, wave, lane, hf_s, xv, ss);
  // zero halo cols (0,65) of all 10 rows, both parities: 80 cells
  if (tid < 80) {
    const int par = tid & 1, col = ((tid >> 1) & 1) * 65;
    const int hf2 = (tid >> 2) & 1, hr2 = tid >> 3;
    short8 z;
#pragma unroll
    for (int j = 0; j < 8; ++j) z[j] = 0;
    *(short8*)(lds + par * 21120 + ((hr2 * 132) + hf2 * 66 + col) * 16) = z;
  }
  __syncthreads();

  for (int ic = 0; ic < 32; ++ic) {
    const int p = ic & 1;
    if (ic + 1 < 32) {     // issue next chunk's x loads + w staging
      stage_x_load(xb, s, b, ic + 1, h0, wave, lane, hf_s, xv, ss);
      const char* wsr = wsrc0 + (size_t)(ic + 1) * 147456;
      char* wd = lds + 42240 + (p ^ 1) * 36864;
#pragma unroll
      for (int k = 0; k < 4; ++k) {
        const int j = tid + k * 512;
        async_load16(wsr + j * 16, wd + j * 16);
      }
      if (tid < 256) { const int j = 2048 + tid; async_load16(wsr + j * 16, wd + j * 16); }
    }
    const char* xp = lds + p * 21120;
    const char* wp = lds + 42240 + p * 36864;

    // chunk-top fill: brow for dseq[0] and A for first cluster
    short8 br[2][6];
#pragma unroll
    for (int rr = 0; rr < 6; ++rr)
      br[0][rr] = *(const short8*)(
          xp + (((r0 + rr) * 132) + half * 66 + c0 + dseq[0] + l31) * 16);
    short8 a_cur[2], a_nxt[2];
#pragma unroll
    for (int f = 0; f < 2; ++f)
      a_cur[f] = *(const short8*)(
          wp + dseq[0] * 4096 + half * 2048 + (oh * 64 + f * 32 + l31) * 16);

#pragma unroll
    for (int dwi = 0; dwi < 3; ++dwi) {
      const int cb = dwi & 1, nb = cb ^ 1;
      if (dwi < 2) {      // pipeline B: issue next dw-phase's 6 rows now
        const int dwn = dseq[dwi + 1];
#pragma unroll
        for (int rr = 0; rr < 6; ++rr)
          br[nb][rr] = *(const short8*)(
              xp + (((r0 + rr) * 132) + half * 66 + c0 + dwn + l31) * 16);
      }
#pragma unroll
      for (int dh = 0; dh < 3; ++dh) {
        if (!(dwi == 2 && dh == 2)) {   // pipeline A: next cluster's fragments
          const int dh_n = (dh < 2) ? dh + 1 : 0;
          const int dw_n = (dh < 2) ? dseq[dwi] : dseq[dwi + 1];
#pragma unroll
          for (int f = 0; f < 2; ++f)
            a_nxt[f] = *(const short8*)(
                wp + (dh_n * 3 + dw_n) * 4096 + half * 2048 + (oh * 64 + f * 32 + l31) * 16);
        }
        __builtin_amdgcn_s_setprio(1);
#pragma unroll
        for (int tpr = 0; tpr < 4; ++tpr)
#pragma unroll
          for (int f = 0; f < 2; ++f)
            acc[f][tpr] = __builtin_amdgcn_mfma_f32_32x32x16_bf16(
                a_cur[f], br[cb][tpr + dh], acc[f][tpr], 0, 0, 0);
        __builtin_amdgcn_s_setprio(0);
        a_cur[0] = a_nxt[0]; a_cur[1] = a_nxt[1];
      }
    }

    if (ic + 1 < 32)       // convert + write next chunk's x into parity p^1
      stage_x_write(lds + (p ^ 1) * 21120, wave, lane, hf_s, xv, ss);
    __syncthreads();
  }

  // epilogue: o = o0 + oh*64 + f*32 + (reg&3) + 8*(reg>>2) + 4*half
#pragma unroll
  for (int f = 0; f < 2; ++f) {
#pragma unroll
    for (int g = 0; g < 4; ++g) {
#pragma unroll
      for (int r = 0; r < 4; ++r) {
        const int o = o0 + oh * 64 + f * 32 + r + 8 * g + 4 * half;
        const float sig  = sigma_inv[b * OUT_F + o];
        const float bias = b_conv[o];
        const int reg = g * 4 + r;
#pragma unroll
        for (int tpr = 0; tpr < 4; ++tpr) {
          const int h = h0 + r0 + tpr;
          const int w = c0 + l31;
          out[(((size_t)(b * OUT_F + o) * RES + h) * RES) + w] =
              acc[f][tpr][reg] * sig + bias;
        }
      }
    }
  }
}

extern "C" void kernel_launch(void* const* d_in, const int* in_sizes, int n_in,
                              void* d_out, int out_size, void* d_ws, size_t ws_size,
                              hipStream_t stream) {
  const float* x      = (const float*)d_in[0];
  const float* latent = (const float*)d_in[1];
  const float* w_lin  = (const float*)d_in[2];
  const float* b_lin  = (const float*)d_in[3];
  const float* w_conv = (const float*)d_in[4];
  const float* b_conv = (const float*)d_in[5];
  float* out = (float*)d_out;

  char* ws = (char*)d_ws;
  short* wb        = (short*)ws;                    //  4,718,592 B
  float* w2        = (float*)(ws + 4718592);        //  1,048,576 B
  float* s         = (float*)(ws + 5767168);        //     16,384 B
  float* sigma_inv = (float*)(ws + 5783552);        //     16,384 B

  k_prep<<<1024, 256, 0, stream>>>(w_conv, wb, w2, latent, w_lin, b_lin, s);
  k_sigma<<<128, 256, 0, stream>>>(w2, s, sigma_inv);
  k_conv<<<256, 512, 0, stream>>>(x, s, wb, sigma_inv, b_conv, out);
}

// Round 12
// 247.948 us; speedup vs baseline: 1.0273x; 1.0273x over previous
//
#include <hip/hip_runtime.h>
#include <hip/hip_bf16.h>

#define IN_F 512
#define OUT_F 512
#define LATD 512
#define RES 64
#define BATCH 8
#define EPSV 1e-8f

static constexpr float C_LIN  = 0.04419417382415922f;   // 1/sqrt(512)
static constexpr float C_CONV = 0.014731391274719739f;  // 1/sqrt(512*9)

typedef __attribute__((ext_vector_type(8)))  short short8;
typedef __attribute__((ext_vector_type(16))) float f32x16;

union BF { __hip_bfloat16 h; short s; };

__device__ __forceinline__ void async_load16(const char* g, char* l) {
  __builtin_amdgcn_global_load_lds(
      (const __attribute__((address_space(1))) unsigned int*)g,
      (__attribute__((address_space(3))) unsigned int*)l, 16, 0, 0);
}

// ================= K1: prep_w (coalesced, LDS transpose) + border + compute_s =========
// Grid 256. Block B: zero halo border of xmp plane B (all blocks).
// Blocks <128: build wb region B=(c*4+ob) via LDS transpose + w2 + compute_s.
// wb layout: [(c*4+ob)][tap][hf][ol:128][ch:8] bf16.
__global__ void k_prep(const float* __restrict__ w_conv,
                       short* __restrict__ wb,
                       float* __restrict__ w2,
                       char* __restrict__ xmp,
                       const float* __restrict__ latent,
                       const float* __restrict__ w_lin,
                       const float* __restrict__ b_lin,
                       float* __restrict__ s) {
  const int B = blockIdx.x;
  const int tid = threadIdx.x;

  // halo-border zeroing: plane layout [66][2][66][16B] (one plane per block)
  {
    char* base = xmp + (size_t)B * 139392;
    for (int q = tid; q < 520; q += 256) {
      int h, hf, w;
      if (q < 132)      { h = 0;  hf = (q >= 66) ? 1 : 0; w = q - hf * 66; }
      else if (q < 264) { const int r = q - 132; h = 65; hf = (r >= 66) ? 1 : 0; w = r - hf * 66; }
      else              { const int r = q - 264; h = (r >> 2) + 1; hf = (r >> 1) & 1; w = (r & 1) * 65; }
      *(uint4*)(base + ((size_t)(h * 132 + hf * 66 + w)) * 16) = make_uint4(0u, 0u, 0u, 0u);
    }
  }

  if (B >= 128) return;

  // ---- wb transpose for region B = c*4 + ob ----
  const int c = B >> 2, ob = B & 3;
  __shared__ short wl[9 * 2048];          // 36,864 B, final [tap][hf][ol][ch] layout
#pragma unroll
  for (int it = 0; it < 8; ++it) {
    const int p  = it * 256 + tid;        // 0..2047
    const int ol = p >> 4, il = p & 15;
    const int hf = il >> 3, ch = il & 7;
    const int o  = ob * 128 + ol;
    const int i  = c * 16 + il;
    const float* src = w_conv + ((size_t)o * 512 + i) * 9;
    float sum = 0.f;
#pragma unroll
    for (int tap = 0; tap < 9; ++tap) {
      const float v = src[tap] * C_CONV;
      sum += v * v;
      BF cv; cv.h = __float2bfloat16(v);
      wl[tap * 2048 + hf * 1024 + ol * 8 + ch] = cv.s;
    }
    w2[(size_t)o * 512 + i] = sum;        // exact f32 sums (numerics unchanged)
  }
  __syncthreads();
  // coalesced write-out: 9 passes x 4KB contiguous
  short* dst = wb + (size_t)B * 18432;
#pragma unroll
  for (int pass = 0; pass < 9; ++pass)
    *(short8*)(dst + pass * 2048 + tid * 8) = *(const short8*)(wl + pass * 2048 + tid * 8);

  // ---- compute_s: wave wv -> row i = B*4 + wv ----
  {
    const int wv = tid >> 6, lane = tid & 63;
    const int i = B * 4 + wv;
    const float4* wlr = (const float4*)(w_lin + (size_t)i * LATD);
    const float4 w0 = wlr[lane * 2], w1 = wlr[lane * 2 + 1];
    float acc[BATCH];
#pragma unroll
    for (int b = 0; b < BATCH; ++b) {
      const float4* lt = (const float4*)(latent + (size_t)b * LATD);
      const float4 l0 = lt[lane * 2], l1 = lt[lane * 2 + 1];
      acc[b] = w0.x * l0.x + w0.y * l0.y + w0.z * l0.z + w0.w * l0.w +
               w1.x * l1.x + w1.y * l1.y + w1.z * l1.z + w1.w * l1.w;
    }
#pragma unroll
    for (int b = 0; b < BATCH; ++b) {
      float v = acc[b];
#pragma unroll
      for (int off = 32; off > 0; off >>= 1) v += __shfl_down(v, off);
      if (lane == 0) s[b * IN_F + i] = v * C_LIN + b_lin[i];
    }
  }
}

// ===== K2: blocks 0..127 sigma_inv ; blocks 128..1151 modulate (8 h-rows per block) =====
__global__ void k_mod_sigma(const float* __restrict__ x,
                            const float* __restrict__ s,
                            char* __restrict__ xmp,
                            const float* __restrict__ w2,
                            float* __restrict__ sigma_inv) {
  if (blockIdx.x < 128) {
    const int o = blockIdx.x * 4 + (threadIdx.x >> 6);
    const int lane = threadIdx.x & 63;
    float acc[BATCH];
#pragma unroll
    for (int b = 0; b < BATCH; ++b) acc[b] = 0.f;
#pragma unroll
    for (int k = 0; k < 8; ++k) {
      const int i = k * 64 + lane;
      const float w = w2[o * IN_F + i];
#pragma unroll
      for (int b = 0; b < BATCH; ++b) {
        const float sv = s[b * IN_F + i];
        acc[b] += w * sv * sv;
      }
    }
#pragma unroll
    for (int b = 0; b < BATCH; ++b) {
      float v = acc[b];
#pragma unroll
      for (int off = 32; off > 0; off >>= 1) v += __shfl_down(v, off);
      if (lane == 0) sigma_inv[b * OUT_F + o] = rsqrtf(v + EPSV);
    }
    return;
  }
  // modulate: bid -> (b, ic32, h8); each block does 8 consecutive h rows.
  const int bid  = blockIdx.x - 128;       // 0..1023
  const int h8   = bid & 7;
  const int ic32 = (bid >> 3) & 15;
  const int b    = bid >> 7;
  __shared__ float tile[32][65];
  const int tid = threadIdx.x;
  const int il = tid >> 3, w8 = (tid & 7) * 8;
  const int i  = ic32 * 32 + il;
  const float sv = s[b * IN_F + i];
  const float* xrow = x + (size_t)(b * IN_F + i) * (RES * RES) + w8;
  const int w = tid >> 2, part = tid & 3;
  const int chalf = part >> 1, hf = part & 1;
  const int c = ic32 * 2 + chalf;
  char* dstb = xmp + (size_t)(c * 8 + b) * 139392 + ((size_t)hf * 66 + (w + 1)) * 16;

  float4 v0 = *(const float4*)(xrow + (size_t)(h8 * 8) * RES);
  float4 v1 = *(const float4*)(xrow + (size_t)(h8 * 8) * RES + 4);
#pragma unroll
  for (int hh = 0; hh < 8; ++hh) {
    const int h = h8 * 8 + hh;
    tile[il][w8 + 0] = v0.x * sv; tile[il][w8 + 1] = v0.y * sv;
    tile[il][w8 + 2] = v0.z * sv; tile[il][w8 + 3] = v0.w * sv;
    tile[il][w8 + 4] = v1.x * sv; tile[il][w8 + 5] = v1.y * sv;
    tile[il][w8 + 6] = v1.z * sv; tile[il][w8 + 7] = v1.w * sv;
    float4 n0, n1;
    if (hh < 7) {        // issue next row's load before the barriers
      n0 = *(const float4*)(xrow + (size_t)(h + 1) * RES);
      n1 = *(const float4*)(xrow + (size_t)(h + 1) * RES + 4);
    }
    __syncthreads();
    short8 pk;
#pragma unroll
    for (int j = 0; j < 8; ++j) {
      BF cv; cv.h = __float2bfloat16(tile[chalf * 16 + hf * 8 + j][w]);
      pk[j] = cv.s;
    }
    *(short8*)(dstb + (size_t)(h + 1) * 2112) = pk;
    __syncthreads();
    v0 = n0; v1 = n1;
  }
}

// ---------------- main implicit-GEMM conv (round-9 best: ~122 us) ----------------
// Block: 128 o x (8 rows x 64 cols) px, 8 waves (512 thr) -> 2 waves/SIMD.
// Wave = 64 o x (4 rows x 32 cols). A+B from LDS; B reg-double-buffered one
// dw-phase ahead; A pipelined one cluster ahead; setprio around MFMA.
__global__ __launch_bounds__(512, 2)
void k_conv(const char* __restrict__ xmp,
            const short* __restrict__ wbg,
            const float* __restrict__ sigma_inv,
            const float* __restrict__ b_conv,
            float* __restrict__ out) {
  __shared__ __align__(16) char lds[115968];  // x: 2*21120 @0, w: 2*36864 @42240
  const int l = blockIdx.x;
  const int ob = (l >> 3) & 3;
  const int b  = l & 7;
  const int h0 = (l >> 5) * 8;
  const int o0 = ob * 128;
  const int tid = threadIdx.x;
  const int wave = tid >> 6, lane = tid & 63;
  const int l31 = lane & 31, half = lane >> 5;
  const int oh = wave >> 2;             // o-half
  const int q  = wave & 3;              // px quadrant
  const int r0 = (q >> 1) * 4;
  const int c0 = (q & 1) * 32;
  const int st = (wave >> 2) & 1;       // dw-phase stagger
  const int dseq[3] = {st, st + 1, st ? 0 : 2};

  f32x16 acc[2][4];
#pragma unroll
  for (int i = 0; i < 2; ++i)
#pragma unroll
    for (int j = 0; j < 4; ++j)
#pragma unroll
      for (int r = 0; r < 16; ++r) acc[i][j][r] = 0.f;

  const char* xsrc0 = xmp + (size_t)b * 139392 + (size_t)h0 * 2112;
  const char* wsrc0 = (const char*)wbg + (size_t)ob * 36864;

  // stage chunk 0 into parity 0 (512 threads)
#pragma unroll
  for (int k = 0; k < 2; ++k) {
    const int j = tid + k * 512;
    async_load16(xsrc0 + j * 16, lds + j * 16);
  }
  if (tid < 296) { const int j = 1024 + tid; async_load16(xsrc0 + j * 16, lds + j * 16); }
#pragma unroll
  for (int k = 0; k < 4; ++k) {
    const int j = tid + k * 512;
    async_load16(wsrc0 + j * 16, lds + 42240 + j * 16);
  }
  if (tid < 256) { const int j = 2048 + tid; async_load16(wsrc0 + j * 16, lds + 42240 + j * 16); }
  __syncthreads();

  for (int ic = 0; ic < 32; ++ic) {
    const int p = ic & 1;
    if (ic + 1 < 32) {
      const char* xs  = xsrc0 + (size_t)(ic + 1) * (8 * 139392);
      const char* wsr = wsrc0 + (size_t)(ic + 1) * 147456;
      char* xd = lds + (p ^ 1) * 21120;
      char* wd = lds + 42240 + (p ^ 1) * 36864;
#pragma unroll
      for (int k = 0; k < 2; ++k) {
        const int j = tid + k * 512;
        async_load16(xs + j * 16, xd + j * 16);
      }
      if (tid < 296) { const int j = 1024 + tid; async_load16(xs + j * 16, xd + j * 16); }
#pragma unroll
      for (int k = 0; k < 4; ++k) {
        const int j = tid + k * 512;
        async_load16(wsr + j * 16, wd + j * 16);
      }
      if (tid < 256) { const int j = 2048 + tid; async_load16(wsr + j * 16, wd + j * 16); }
    }
    const char* xp = lds + p * 21120;
    const char* wp = lds + 42240 + p * 36864;

    // chunk-top fill: brow for dseq[0] and A for first cluster
    short8 br[2][6];
#pragma unroll
    for (int rr = 0; rr < 6; ++rr)
      br[0][rr] = *(const short8*)(
          xp + (((r0 + rr) * 132) + half * 66 + c0 + dseq[0] + l31) * 16);
    short8 a_cur[2], a_nxt[2];
#pragma unroll
    for (int f = 0; f < 2; ++f)
      a_cur[f] = *(const short8*)(
          wp + dseq[0] * 4096 + half * 2048 + (oh * 64 + f * 32 + l31) * 16);

#pragma unroll
    for (int dwi = 0; dwi < 3; ++dwi) {
      const int cb = dwi & 1, nb = cb ^ 1;
      if (dwi < 2) {      // pipeline B: issue next dw-phase's 6 rows now
        const int dwn = dseq[dwi + 1];
#pragma unroll
        for (int rr = 0; rr < 6; ++rr)
          br[nb][rr] = *(const short8*)(
              xp + (((r0 + rr) * 132) + half * 66 + c0 + dwn + l31) * 16);
      }
#pragma unroll
      for (int dh = 0; dh < 3; ++dh) {
        if (!(dwi == 2 && dh == 2)) {   // pipeline A: next cluster's fragments
          const int dh_n = (dh < 2) ? dh + 1 : 0;
          const int dw_n = (dh < 2) ? dseq[dwi] : dseq[dwi + 1];
#pragma unroll
          for (int f = 0; f < 2; ++f)
            a_nxt[f] = *(const short8*)(
                wp + (dh_n * 3 + dw_n) * 4096 + half * 2048 + (oh * 64 + f * 32 + l31) * 16);
        }
        __builtin_amdgcn_s_setprio(1);
#pragma unroll
        for (int tpr = 0; tpr < 4; ++tpr)
#pragma unroll
          for (int f = 0; f < 2; ++f)
            acc[f][tpr] = __builtin_amdgcn_mfma_f32_32x32x16_bf16(
                a_cur[f], br[cb][tpr + dh], acc[f][tpr], 0, 0, 0);
        __builtin_amdgcn_s_setprio(0);
        a_cur[0] = a_nxt[0]; a_cur[1] = a_nxt[1];
      }
    }
    __syncthreads();
  }

  // epilogue: o = o0 + oh*64 + f*32 + (reg&3) + 8*(reg>>2) + 4*half
#pragma unroll
  for (int f = 0; f < 2; ++f) {
#pragma unroll
    for (int g = 0; g < 4; ++g) {
#pragma unroll
      for (int r = 0; r < 4; ++r) {
        const int o = o0 + oh * 64 + f * 32 + r + 8 * g + 4 * half;
        const float sig  = sigma_inv[b * OUT_F + o];
        const float bias = b_conv[o];
        const int reg = g * 4 + r;
#pragma unroll
        for (int tpr = 0; tpr < 4; ++tpr) {
          const int h = h0 + r0 + tpr;
          const int w = c0 + l31;
          out[(((size_t)(b * OUT_F + o) * RES + h) * RES) + w] =
              acc[f][tpr][reg] * sig + bias;
        }
      }
    }
  }
}

extern "C" void kernel_launch(void* const* d_in, const int* in_sizes, int n_in,
                              void* d_out, int out_size, void* d_ws, size_t ws_size,
                              hipStream_t stream) {
  const float* x      = (const float*)d_in[0];
  const float* latent = (const float*)d_in[1];
  const float* w_lin  = (const float*)d_in[2];
  const float* b_lin  = (const float*)d_in[3];
  const float* w_conv = (const float*)d_in[4];
  const float* b_conv = (const float*)d_in[5];
  float* out = (float*)d_out;

  char* ws = (char*)d_ws;
  char*  xmp       = ws;                            // 35,684,352 B (256 planes x 66*2*66*16)
  short* wb        = (short*)(ws + 35684352);       //  4,718,592 B
  float* w2        = (float*)(ws + 40402944);       //  1,048,576 B
  float* s         = (float*)(ws + 41451520);       //     16,384 B
  float* sigma_inv = (float*)(ws + 41467904);       //     16,384 B

  k_prep<<<256, 256, 0, stream>>>(w_conv, wb, w2, xmp, latent, w_lin, b_lin, s);
  k_mod_sigma<<<128 + 1024, 256, 0, stream>>>(x, s, xmp, w2, sigma_inv);
  k_conv<<<256, 512, 0, stream>>>(xmp, wb, sigma_inv, b_conv, out);
}

// Round 13
// 243.757 us; speedup vs baseline: 1.0449x; 1.0172x over previous
//
#include <hip/hip_runtime.h>
#include <hip/hip_bf16.h>

#define IN_F 512
#define OUT_F 512
#define LATD 512
#define RES 64
#define BATCH 8
#define EPSV 1e-8f

static constexpr float C_LIN  = 0.04419417382415922f;   // 1/sqrt(512)
static constexpr float C_CONV = 0.014731391274719739f;  // 1/sqrt(512*9)

typedef __attribute__((ext_vector_type(8)))  short short8;
typedef __attribute__((ext_vector_type(16))) float f32x16;

union BF { __hip_bfloat16 h; short s; };

__device__ __forceinline__ void async_load16(const char* g, char* l) {
  __builtin_amdgcn_global_load_lds(
      (const __attribute__((address_space(1))) unsigned int*)g,
      (__attribute__((address_space(3))) unsigned int*)l, 16, 0, 0);
}

// ================= K1: prep_w (coalesced, LDS transpose) + border + compute_s =========
__global__ void k_prep(const float* __restrict__ w_conv,
                       short* __restrict__ wb,
                       float* __restrict__ w2,
                       char* __restrict__ xmp,
                       const float* __restrict__ latent,
                       const float* __restrict__ w_lin,
                       const float* __restrict__ b_lin,
                       float* __restrict__ s) {
  const int B = blockIdx.x;
  const int tid = threadIdx.x;

  // halo-border zeroing: plane layout [66][2][66][16B] (one plane per block)
  {
    char* base = xmp + (size_t)B * 139392;
    for (int q = tid; q < 520; q += 256) {
      int h, hf, w;
      if (q < 132)      { h = 0;  hf = (q >= 66) ? 1 : 0; w = q - hf * 66; }
      else if (q < 264) { const int r = q - 132; h = 65; hf = (r >= 66) ? 1 : 0; w = r - hf * 66; }
      else              { const int r = q - 264; h = (r >> 2) + 1; hf = (r >> 1) & 1; w = (r & 1) * 65; }
      *(uint4*)(base + ((size_t)(h * 132 + hf * 66 + w)) * 16) = make_uint4(0u, 0u, 0u, 0u);
    }
  }

  if (B >= 128) return;

  // ---- wb transpose for region B = c*4 + ob ----
  const int c = B >> 2, ob = B & 3;
  __shared__ short wl[9 * 2048];          // 36,864 B, final [tap][hf][ol][ch] layout
#pragma unroll
  for (int it = 0; it < 8; ++it) {
    const int p  = it * 256 + tid;        // 0..2047
    const int ol = p >> 4, il = p & 15;
    const int hf = il >> 3, ch = il & 7;
    const int o  = ob * 128 + ol;
    const int i  = c * 16 + il;
    const float* src = w_conv + ((size_t)o * 512 + i) * 9;
    float sum = 0.f;
#pragma unroll
    for (int tap = 0; tap < 9; ++tap) {
      const float v = src[tap] * C_CONV;
      sum += v * v;
      BF cv; cv.h = __float2bfloat16(v);
      wl[tap * 2048 + hf * 1024 + ol * 8 + ch] = cv.s;
    }
    w2[(size_t)o * 512 + i] = sum;        // exact f32 sums (numerics unchanged)
  }
  __syncthreads();
  // coalesced write-out: 9 passes x 4KB contiguous
  short* dst = wb + (size_t)B * 18432;
#pragma unroll
  for (int pass = 0; pass < 9; ++pass)
    *(short8*)(dst + pass * 2048 + tid * 8) = *(const short8*)(wl + pass * 2048 + tid * 8);

  // ---- compute_s: wave wv -> row i = B*4 + wv ----
  {
    const int wv = tid >> 6, lane = tid & 63;
    const int i = B * 4 + wv;
    const float4* wlr = (const float4*)(w_lin + (size_t)i * LATD);
    const float4 w0 = wlr[lane * 2], w1 = wlr[lane * 2 + 1];
    float acc[BATCH];
#pragma unroll
    for (int b = 0; b < BATCH; ++b) {
      const float4* lt = (const float4*)(latent + (size_t)b * LATD);
      const float4 l0 = lt[lane * 2], l1 = lt[lane * 2 + 1];
      acc[b] = w0.x * l0.x + w0.y * l0.y + w0.z * l0.z + w0.w * l0.w +
               w1.x * l1.x + w1.y * l1.y + w1.z * l1.z + w1.w * l1.w;
    }
#pragma unroll
    for (int b = 0; b < BATCH; ++b) {
      float v = acc[b];
#pragma unroll
      for (int off = 32; off > 0; off >>= 1) v += __shfl_down(v, off);
      if (lane == 0) s[b * IN_F + i] = v * C_LIN + b_lin[i];
    }
  }
}

// ===== K2: blocks 0..127 sigma_inv ; blocks 128..2175 modulate (4 h-rows per block) =====
__global__ void k_mod_sigma(const float* __restrict__ x,
                            const float* __restrict__ s,
                            char* __restrict__ xmp,
                            const float* __restrict__ w2,
                            float* __restrict__ sigma_inv) {
  if (blockIdx.x < 128) {
    const int o = blockIdx.x * 4 + (threadIdx.x >> 6);
    const int lane = threadIdx.x & 63;
    float acc[BATCH];
#pragma unroll
    for (int b = 0; b < BATCH; ++b) acc[b] = 0.f;
#pragma unroll
    for (int k = 0; k < 8; ++k) {
      const int i = k * 64 + lane;
      const float w = w2[o * IN_F + i];
#pragma unroll
      for (int b = 0; b < BATCH; ++b) {
        const float sv = s[b * IN_F + i];
        acc[b] += w * sv * sv;
      }
    }
#pragma unroll
    for (int b = 0; b < BATCH; ++b) {
      float v = acc[b];
#pragma unroll
      for (int off = 32; off > 0; off >>= 1) v += __shfl_down(v, off);
      if (lane == 0) sigma_inv[b * OUT_F + o] = rsqrtf(v + EPSV);
    }
    return;
  }
  // modulate: bid -> (b, ic32, h4); each block does 4 consecutive h rows.
  const int bid  = blockIdx.x - 128;       // 0..2047
  const int h4   = bid & 15;
  const int ic32 = (bid >> 4) & 15;
  const int b    = bid >> 8;
  __shared__ float tile[32][65];
  const int tid = threadIdx.x;
  const int il = tid >> 3, w8 = (tid & 7) * 8;
  const int i  = ic32 * 32 + il;
  const float sv = s[b * IN_F + i];
  const float* xrow = x + (size_t)(b * IN_F + i) * (RES * RES) + w8;
  const int w = tid >> 2, part = tid & 3;
  const int chalf = part >> 1, hf = part & 1;
  const int c = ic32 * 2 + chalf;
  char* dstb = xmp + (size_t)(c * 8 + b) * 139392 + ((size_t)hf * 66 + (w + 1)) * 16;

  float4 v0 = *(const float4*)(xrow + (size_t)(h4 * 4) * RES);
  float4 v1 = *(const float4*)(xrow + (size_t)(h4 * 4) * RES + 4);
#pragma unroll
  for (int hh = 0; hh < 4; ++hh) {
    const int h = h4 * 4 + hh;
    tile[il][w8 + 0] = v0.x * sv; tile[il][w8 + 1] = v0.y * sv;
    tile[il][w8 + 2] = v0.z * sv; tile[il][w8 + 3] = v0.w * sv;
    tile[il][w8 + 4] = v1.x * sv; tile[il][w8 + 5] = v1.y * sv;
    tile[il][w8 + 6] = v1.z * sv; tile[il][w8 + 7] = v1.w * sv;
    float4 n0, n1;
    if (hh < 3) {        // issue next row's load before the barriers
      n0 = *(const float4*)(xrow + (size_t)(h + 1) * RES);
      n1 = *(const float4*)(xrow + (size_t)(h + 1) * RES + 4);
    }
    __syncthreads();
    short8 pk;
#pragma unroll
    for (int j = 0; j < 8; ++j) {
      BF cv; cv.h = __float2bfloat16(tile[chalf * 16 + hf * 8 + j][w]);
      pk[j] = cv.s;
    }
    *(short8*)(dstb + (size_t)(h + 1) * 2112) = pk;
    __syncthreads();
    v0 = n0; v1 = n1;
  }
}

// ---------------- main implicit-GEMM conv ----------------
// Block: 128 o x (8 rows x 64 cols) px, 8 waves (512 thr) -> 2 waves/SIMD.
// NEW: time-skew — waves 4-7 (SIMD partners of waves 0-3) s_sleep(3) (~192cy)
// at each chunk top so SIMD-paired waves are anti-phased: one reads LDS while
// the other MFMAs. Targets the measured serialization (chunk = 4650 MFMA +
// 3456 LDS back-to-back; address-level stagger/pipelining didn't fix TIME).
__global__ __launch_bounds__(512, 2)
void k_conv(const char* __restrict__ xmp,
            const short* __restrict__ wbg,
            const float* __restrict__ sigma_inv,
            const float* __restrict__ b_conv,
            float* __restrict__ out) {
  __shared__ __align__(16) char lds[115968];  // x: 2*21120 @0, w: 2*36864 @42240
  const int l = blockIdx.x;
  const int ob = (l >> 3) & 3;
  const int b  = l & 7;
  const int h0 = (l >> 5) * 8;
  const int o0 = ob * 128;
  const int tid = threadIdx.x;
  const int wave = tid >> 6, lane = tid & 63;
  const int l31 = lane & 31, half = lane >> 5;
  const int oh = wave >> 2;             // o-half
  const int q  = wave & 3;              // px quadrant
  const int r0 = (q >> 1) * 4;
  const int c0 = (q & 1) * 32;
  const int st = (wave >> 2) & 1;       // dw-phase stagger
  const int dseq[3] = {st, st + 1, st ? 0 : 2};

  f32x16 acc[2][4];
#pragma unroll
  for (int i = 0; i < 2; ++i)
#pragma unroll
    for (int j = 0; j < 4; ++j)
#pragma unroll
      for (int r = 0; r < 16; ++r) acc[i][j][r] = 0.f;

  const char* xsrc0 = xmp + (size_t)b * 139392 + (size_t)h0 * 2112;
  const char* wsrc0 = (const char*)wbg + (size_t)ob * 36864;

  // stage chunk 0 into parity 0 (512 threads)
#pragma unroll
  for (int k = 0; k < 2; ++k) {
    const int j = tid + k * 512;
    async_load16(xsrc0 + j * 16, lds + j * 16);
  }
  if (tid < 296) { const int j = 1024 + tid; async_load16(xsrc0 + j * 16, lds + j * 16); }
#pragma unroll
  for (int k = 0; k < 4; ++k) {
    const int j = tid + k * 512;
    async_load16(wsrc0 + j * 16, lds + 42240 + j * 16);
  }
  if (tid < 256) { const int j = 2048 + tid; async_load16(wsrc0 + j * 16, lds + 42240 + j * 16); }
  __syncthreads();

  for (int ic = 0; ic < 32; ++ic) {
    // anti-phase the SIMD-paired wave: it sleeps ~192cy while its partner
    // fills registers and enters MFMA; pair stays skewed until chunk barrier.
    if (wave & 4) __builtin_amdgcn_s_sleep(3);
    const int p = ic & 1;
    if (ic + 1 < 32) {
      const char* xs  = xsrc0 + (size_t)(ic + 1) * (8 * 139392);
      const char* wsr = wsrc0 + (size_t)(ic + 1) * 147456;
      char* xd = lds + (p ^ 1) * 21120;
      char* wd = lds + 42240 + (p ^ 1) * 36864;
#pragma unroll
      for (int k = 0; k < 2; ++k) {
        const int j = tid + k * 512;
        async_load16(xs + j * 16, xd + j * 16);
      }
      if (tid < 296) { const int j = 1024 + tid; async_load16(xs + j * 16, xd + j * 16); }
#pragma unroll
      for (int k = 0; k < 4; ++k) {
        const int j = tid + k * 512;
        async_load16(wsr + j * 16, wd + j * 16);
      }
      if (tid < 256) { const int j = 2048 + tid; async_load16(wsr + j * 16, wd + j * 16); }
    }
    const char* xp = lds + p * 21120;
    const char* wp = lds + 42240 + p * 36864;

    // chunk-top fill: brow for dseq[0] and A for first cluster
    short8 br[2][6];
#pragma unroll
    for (int rr = 0; rr < 6; ++rr)
      br[0][rr] = *(const short8*)(
          xp + (((r0 + rr) * 132) + half * 66 + c0 + dseq[0] + l31) * 16);
    short8 a_cur[2], a_nxt[2];
#pragma unroll
    for (int f = 0; f < 2; ++f)
      a_cur[f] = *(const short8*)(
          wp + dseq[0] * 4096 + half * 2048 + (oh * 64 + f * 32 + l31) * 16);

#pragma unroll
    for (int dwi = 0; dwi < 3; ++dwi) {
      const int cb = dwi & 1, nb = cb ^ 1;
      if (dwi < 2) {      // pipeline B: issue next dw-phase's 6 rows now
        const int dwn = dseq[dwi + 1];
#pragma unroll
        for (int rr = 0; rr < 6; ++rr)
          br[nb][rr] = *(const short8*)(
              xp + (((r0 + rr) * 132) + half * 66 + c0 + dwn + l31) * 16);
      }
#pragma unroll
      for (int dh = 0; dh < 3; ++dh) {
        if (!(dwi == 2 && dh == 2)) {   // pipeline A: next cluster's fragments
          const int dh_n = (dh < 2) ? dh + 1 : 0;
          const int dw_n = (dh < 2) ? dseq[dwi] : dseq[dwi + 1];
#pragma unroll
          for (int f = 0; f < 2; ++f)
            a_nxt[f] = *(const short8*)(
                wp + (dh_n * 3 + dw_n) * 4096 + half * 2048 + (oh * 64 + f * 32 + l31) * 16);
        }
        __builtin_amdgcn_s_setprio(1);
#pragma unroll
        for (int tpr = 0; tpr < 4; ++tpr)
#pragma unroll
          for (int f = 0; f < 2; ++f)
            acc[f][tpr] = __builtin_amdgcn_mfma_f32_32x32x16_bf16(
                a_cur[f], br[cb][tpr + dh], acc[f][tpr], 0, 0, 0);
        __builtin_amdgcn_s_setprio(0);
        a_cur[0] = a_nxt[0]; a_cur[1] = a_nxt[1];
      }
    }
    __syncthreads();
  }

  // epilogue: o = o0 + oh*64 + f*32 + (reg&3) + 8*(reg>>2) + 4*half
#pragma unroll
  for (int f = 0; f < 2; ++f) {
#pragma unroll
    for (int g = 0; g < 4; ++g) {
#pragma unroll
      for (int r = 0; r < 4; ++r) {
        const int o = o0 + oh * 64 + f * 32 + r + 8 * g + 4 * half;
        const float sig  = sigma_inv[b * OUT_F + o];
        const float bias = b_conv[o];
        const int reg = g * 4 + r;
#pragma unroll
        for (int tpr = 0; tpr < 4; ++tpr) {
          const int h = h0 + r0 + tpr;
          const int w = c0 + l31;
          out[(((size_t)(b * OUT_F + o) * RES + h) * RES) + w] =
              acc[f][tpr][reg] * sig + bias;
        }
      }
    }
  }
}

extern "C" void kernel_launch(void* const* d_in, const int* in_sizes, int n_in,
                              void* d_out, int out_size, void* d_ws, size_t ws_size,
                              hipStream_t stream) {
  const float* x      = (const float*)d_in[0];
  const float* latent = (const float*)d_in[1];
  const float* w_lin  = (const float*)d_in[2];
  const float* b_lin  = (const float*)d_in[3];
  const float* w_conv = (const float*)d_in[4];
  const float* b_conv = (const float*)d_in[5];
  float* out = (float*)d_out;

  char* ws = (char*)d_ws;
  char*  xmp       = ws;                            // 35,684,352 B (256 planes x 66*2*66*16)
  short* wb        = (short*)(ws + 35684352);       //  4,718,592 B
  float* w2        = (float*)(ws + 40402944);       //  1,048,576 B
  float* s         = (float*)(ws + 41451520);       //     16,384 B
  float* sigma_inv = (float*)(ws + 41467904);       //     16,384 B

  k_prep<<<256, 256, 0, stream>>>(w_conv, wb, w2, xmp, latent, w_lin, b_lin, s);
  k_mod_sigma<<<128 + 2048, 256, 0, stream>>>(x, s, xmp, w2, sigma_inv);
  k_conv<<<256, 512, 0, stream>>>(xmp, wb, sigma_inv, b_conv, out);
}